// Round 9
// baseline (214.128 us; speedup 1.0000x reference)
//
#include <hip/hip_runtime.h>

// SIREN hypernetwork, round 9 = round-8 pipeline at 4-blocks/CU geometry.
// siren_pre: unchanged — W_eff = (ws_h+offset)/2pi, f16, layout
//            [n][l][c(8)][e(256)][k(32)] (linear (l,c) -> running pointer).
// siren_main: 4096 blocks = 16 samples x 256 tiles of 64 points, 256 thr,
//            4 waves = e-quarters (64e x 64p each): et=2, pt=2, acc=64 regs
//            -> VGPR ~124 fits the (256,4) 128-reg cap WITHOUT spill
//            (round 5 failed because 190-reg working set was forced to 64).
//            LDS 39.9 KB -> 4 independent blocks/CU = 4 waves/SIMD.
//            32x32x16 f16 MFMA, register W prefetch, slot^(p&7) swizzle.

#define N_S 16
#define HW_S 16384
#define E_S 263936
#define INV2PI 0.15915494309189535f
#define OM2PI  4.774648292756860f   // 30/(2pi)

typedef _Float16 f16x8 __attribute__((ext_vector_type(8)));
typedef _Float16 f16x4 __attribute__((ext_vector_type(4)));
typedef _Float16 f16x2 __attribute__((ext_vector_type(2)));
typedef float f32x4 __attribute__((ext_vector_type(4)));
typedef float f32x16 __attribute__((ext_vector_type(16)));

// ws layout (bytes)
#define WT_OFF   0u          // f16 [16][4][8][256][32]  (8388608 B)
#define W0T_OFF  8388608u    // f32 [16][256][2]  * 30/2pi
#define B0_OFF   8421376u    // f32 [16][256]     * 30/2pi
#define BE_OFF   8437760u    // f32 [16][4][256]  * 1/2pi

__device__ __forceinline__ float fsin(float z) {
  return __builtin_amdgcn_sinf(__builtin_amdgcn_fractf(z));
}

__global__ __launch_bounds__(256) void siren_pre(
    const float* __restrict__ wo, const float* __restrict__ w0,
    const float* __restrict__ b0, const float* __restrict__ wsh,
    const float* __restrict__ bsh, char* __restrict__ ws)
{
  __shared__ float tile[64][65];
  int b = blockIdx.x, t = threadIdx.x;
  if (b < 1024) {
    int n = b >> 6, rem = b & 63, l = rem >> 4, sub = rem & 15;
    int tk = sub >> 2, te = sub & 3;
    int e_loc = t & 63, ksub = t >> 6;
    const float* wo_n = wo + (size_t)n * E_S + 768 + l * 65792;
    const float* wsh_l = wsh + l * 65536;
    for (int r = 0; r < 16; ++r) {
      int k_loc = ksub * 16 + r;
      int k = tk * 64 + k_loc, e = te * 64 + e_loc;
      tile[k_loc][e_loc] = (wsh_l[k * 256 + e] + wo_n[k * 256 + e]) * INV2PI;
    }
    __syncthreads();
    _Float16* wtl = (_Float16*)(ws + WT_OFF) + (size_t)(n * 4 + l) * 65536;
    int kp = (t & 31) * 2, esub = t >> 5;
    for (int r = 0; r < 8; ++r) {
      int e_loc2 = esub * 8 + r;
      f16x2 hv;
      hv[0] = (_Float16)tile[kp][e_loc2];
      hv[1] = (_Float16)tile[kp + 1][e_loc2];
      int e = te * 64 + e_loc2, k = tk * 64 + kp;
      int c = k >> 5, kin = k & 31;
      *(f16x2*)(wtl + (size_t)c * 8192 + e * 32 + kin) = hv;
    }
  } else if (b == 1024) {
    float* w0t = (float*)(ws + W0T_OFF);
    float* b0e = (float*)(ws + B0_OFF);
    for (int idx = t; idx < 4096; idx += 256) {
      int n = idx >> 8, e = idx & 255;
      const float* wo_n = wo + (size_t)n * E_S;
      float2 v;
      v.x = (w0[e] + wo_n[e]) * OM2PI;
      v.y = (w0[256 + e] + wo_n[256 + e]) * OM2PI;
      *(float2*)(w0t + (n * 256 + e) * 2) = v;
      b0e[n * 256 + e] = (b0[e] + wo_n[512 + e]) * OM2PI;
    }
  } else {
    float* be = (float*)(ws + BE_OFF);
    for (int idx = t; idx < 16384; idx += 256) {
      int n = idx >> 10, rem = idx & 1023, l = rem >> 8, e = rem & 255;
      be[(n * 4 + l) * 256 + e] =
          (bsh[l * 256 + e] + wo[(size_t)n * E_S + 768 + l * 65792 + 65536 + e]) * INV2PI;
    }
  }
}

__global__ __launch_bounds__(256, 4) void siren_main(
    const float* __restrict__ x, const char* __restrict__ ws,
    const float* __restrict__ w_out, const float* __restrict__ b_out,
    const float* __restrict__ out_scale, float* __restrict__ out)
{
  __shared__ __align__(16) unsigned char sH[32768];  // H[64 p][256 e] f16, slot^(p&7) swizzle
  __shared__ float sWf[768];        // w_out [256][3]
  __shared__ float sRed[4][64][3];  // per-wave partials
  __shared__ float sFin[192];       // final [64][3]

  int tid = threadIdx.x;
  int lane = tid & 63, eq = tid >> 6;  // wave = e-quarter (64 e x 64 p)
  int l31 = lane & 31, lh = lane >> 5; // 32x32 fragment row / k-half
  int l317 = l31 & 7;
  int bid = blockIdx.x;
  int n = bid & 15, tile = bid >> 4;   // sample n -> XCD n&7 (L2 locality)

  const char* wt_n = ws + WT_OFF + (size_t)n * 524288;

  // stage w_out once (read only in epilogue)
  for (int i = tid; i < 768; i += 256) sWf[i] = w_out[i];

  // ---- layer 0 in fp32 (weights pre-scaled by 30/2pi) -> sH
  {
    const float* xp = x + ((size_t)n * HW_S + (size_t)tile * 64) * 2;
    int p = tid & 63;
    float2 xv = *(const float2*)(xp + p * 2);
    const float* w0t = (const float*)(ws + W0T_OFF) + n * 512;
    const float* b0e = (const float*)(ws + B0_OFF) + n * 256;
    int swz = (p & 7) << 4;
    unsigned char* hrow = sH + p * 512;
#pragma unroll
    for (int it = 0; it < 8; ++it) {
      int eg = (tid >> 6) * 8 + it;    // 0..31, wave-uniform
      int e0 = eg * 8;
      f32x4 wa = *(const f32x4*)(w0t + e0 * 2);
      f32x4 wb = *(const f32x4*)(w0t + e0 * 2 + 4);
      f32x4 wc = *(const f32x4*)(w0t + e0 * 2 + 8);
      f32x4 wd = *(const f32x4*)(w0t + e0 * 2 + 12);
      f32x4 ba = *(const f32x4*)(b0e + e0);
      f32x4 bb = *(const f32x4*)(b0e + e0 + 4);
      f16x8 hv;
      hv[0] = (_Float16)fsin(fmaf(xv.y, wa[1], fmaf(xv.x, wa[0], ba[0])));
      hv[1] = (_Float16)fsin(fmaf(xv.y, wa[3], fmaf(xv.x, wa[2], ba[1])));
      hv[2] = (_Float16)fsin(fmaf(xv.y, wb[1], fmaf(xv.x, wb[0], ba[2])));
      hv[3] = (_Float16)fsin(fmaf(xv.y, wb[3], fmaf(xv.x, wb[2], ba[3])));
      hv[4] = (_Float16)fsin(fmaf(xv.y, wc[1], fmaf(xv.x, wc[0], bb[0])));
      hv[5] = (_Float16)fsin(fmaf(xv.y, wc[3], fmaf(xv.x, wc[2], bb[1])));
      hv[6] = (_Float16)fsin(fmaf(xv.y, wd[1], fmaf(xv.x, wd[0], bb[2])));
      hv[7] = (_Float16)fsin(fmaf(xv.y, wd[3], fmaf(xv.x, wd[2], bb[3])));
      *(f16x8*)(hrow + ((eg * 16) ^ swz)) = hv;
    }
  }
  __syncthreads();

  const float* be_n = (const float*)(ws + BE_OFF) + n * 1024;

  // afr lane base: e = eq*64 + et*32 + l31, byte = e*64 + lh*16 (+ et*2048 + kh*32 imm)
  const unsigned char* wp =
      (const unsigned char*)wt_n + (eq * 64 + l31) * 64 + lh * 16;

  // bfr lane base (slot-swizzled rows): row l31 (+ pt*16384 via imm)
  const unsigned char* hbase = sH + l31 * 512;

  f32x16 acc[2][2];
  f16x8 a0, a1, a2, a3, n0, n1, n2, n3;
  a0 = *(const f16x8*)(wp + 0);
  a1 = *(const f16x8*)(wp + 32);
  a2 = *(const f16x8*)(wp + 2048);
  a3 = *(const f16x8*)(wp + 2080);

  for (int l = 0; l < 4; ++l) {
    // bias -> acc: e = eq*64 + et*32 + q*8 + lh*4 + j (j=0..3), reg = q*4+j
    const float* bias = be_n + l * 256 + eq * 64 + lh * 4;
#pragma unroll
    for (int et = 0; et < 2; ++et) {
#pragma unroll
      for (int q = 0; q < 4; ++q) {
        f32x4 bv = *(const f32x4*)(bias + et * 32 + q * 8);
#pragma unroll
        for (int j = 0; j < 4; ++j) {
#pragma unroll
          for (int pt = 0; pt < 2; ++pt) acc[et][pt][q * 4 + j] = bv[j];
        }
      }
    }
#pragma unroll
    for (int c = 0; c < 8; ++c) {
      if (c < 7 || l < 3) {  // prefetch next chunk (linear across layers)
        wp += 16384;
        n0 = *(const f16x8*)(wp + 0);
        n1 = *(const f16x8*)(wp + 32);
        n2 = *(const f16x8*)(wp + 2048);
        n3 = *(const f16x8*)(wp + 2080);
      }
      // slot index = c*4 + kh*2 + lh, stored at slot ^ (l31&7)
      int s0 = (((c * 4 + 0) | lh) ^ l317) << 4;
      int s1 = (((c * 4 + 2) | lh) ^ l317) << 4;
      f16x8 b0f[2], b1f[2];
#pragma unroll
      for (int pt = 0; pt < 2; ++pt) {
        b0f[pt] = *(const f16x8*)(hbase + pt * 16384 + s0);
        b1f[pt] = *(const f16x8*)(hbase + pt * 16384 + s1);
      }
#pragma unroll
      for (int pt = 0; pt < 2; ++pt) {
        acc[0][pt] = __builtin_amdgcn_mfma_f32_32x32x16_f16(a0, b0f[pt], acc[0][pt], 0, 0, 0);
        acc[0][pt] = __builtin_amdgcn_mfma_f32_32x32x16_f16(a1, b1f[pt], acc[0][pt], 0, 0, 0);
        acc[1][pt] = __builtin_amdgcn_mfma_f32_32x32x16_f16(a2, b0f[pt], acc[1][pt], 0, 0, 0);
        acc[1][pt] = __builtin_amdgcn_mfma_f32_32x32x16_f16(a3, b1f[pt], acc[1][pt], 0, 0, 0);
      }
      a0 = n0; a1 = n1; a2 = n2; a3 = n3;
    }
    if (l < 3) {
      __syncthreads();  // all waves done reading layer-l H
      unsigned char* wrow = sH + l31 * 512 + lh * 8;
#pragma unroll
      for (int et = 0; et < 2; ++et) {
#pragma unroll
        for (int q = 0; q < 4; ++q) {
          int so = ((eq * 8 + et * 4 + q) ^ l317) << 4;
#pragma unroll
          for (int pt = 0; pt < 2; ++pt) {
            f16x4 hv;
#pragma unroll
            for (int j = 0; j < 4; ++j)
              hv[j] = (_Float16)fsin(acc[et][pt][q * 4 + j]);
            *(f16x4*)(wrow + pt * 16384 + so) = hv;
          }
        }
      }
      __syncthreads();  // new H visible
    }
  }

  // ---- epilogue: h = sin(acc), out = (h @ w_out + b_out) * out_scale
  float part[2][3];
#pragma unroll
  for (int pt = 0; pt < 2; ++pt)
#pragma unroll
    for (int co = 0; co < 3; ++co) part[pt][co] = 0.f;
#pragma unroll
  for (int et = 0; et < 2; ++et) {
#pragma unroll
    for (int q = 0; q < 4; ++q) {
#pragma unroll
      for (int j = 0; j < 4; ++j) {
        int e = eq * 64 + et * 32 + q * 8 + lh * 4 + j;
        float wc0 = sWf[e * 3 + 0], wc1 = sWf[e * 3 + 1], wc2 = sWf[e * 3 + 2];
#pragma unroll
        for (int pt = 0; pt < 2; ++pt) {
          float h = fsin(acc[et][pt][q * 4 + j]);
          part[pt][0] = fmaf(h, wc0, part[pt][0]);
          part[pt][1] = fmaf(h, wc1, part[pt][1]);
          part[pt][2] = fmaf(h, wc2, part[pt][2]);
        }
      }
    }
  }
#pragma unroll
  for (int pt = 0; pt < 2; ++pt)
#pragma unroll
    for (int co = 0; co < 3; ++co)
      part[pt][co] += __shfl_xor(part[pt][co], 32);
  if (lane < 32) {
#pragma unroll
    for (int pt = 0; pt < 2; ++pt) {
      int p = pt * 32 + l31;
#pragma unroll
      for (int co = 0; co < 3; ++co)
        sRed[eq][p][co] = part[pt][co];
    }
  }
  __syncthreads();
  if (tid < 64) {
    int p = tid;
#pragma unroll
    for (int co = 0; co < 3; ++co)
      sFin[p * 3 + co] = (sRed[0][p][co] + sRed[1][p][co] +
                          sRed[2][p][co] + sRed[3][p][co] +
                          b_out[co]) * out_scale[co];
  }
  __syncthreads();
  float* op = out + ((size_t)n * HW_S + (size_t)tile * 64) * 3;
  if (tid < 192) op[tid] = sFin[tid];
}

extern "C" void kernel_launch(void* const* d_in, const int* in_sizes, int n_in,
                              void* d_out, int out_size, void* d_ws, size_t ws_size,
                              hipStream_t stream) {
  const float* x      = (const float*)d_in[0];
  const float* wo     = (const float*)d_in[1];
  const float* w0     = (const float*)d_in[2];
  const float* b0     = (const float*)d_in[3];
  const float* wsh    = (const float*)d_in[4];
  const float* bsh    = (const float*)d_in[5];
  const float* w_out  = (const float*)d_in[6];
  const float* b_out  = (const float*)d_in[7];
  const float* oscale = (const float*)d_in[8];
  float* out = (float*)d_out;
  char* ws = (char*)d_ws;

  siren_pre<<<1026, 256, 0, stream>>>(wo, w0, b0, wsh, bsh, ws);
  siren_main<<<4096, 256, 0, stream>>>(x, ws, w_out, b_out, oscale, out);
}

// Round 10
// 212.233 us; speedup vs baseline: 1.0089x; 1.0089x over previous
//
#include <hip/hip_runtime.h>

// SIREN hypernetwork, round 10 = round-9 geometry, spill-free.
// siren_pre: unchanged — W_eff = (ws_h+offset)/2pi, f16, layout
//            [n][l][c(8)][e(256)][k(32)] (linear (l,c) -> running pointer).
// siren_main: 4096 blocks = 16 samples x 256 tiles of 64 points, 256 thr,
//            4 waves = e-quarters (64e x 64p): et=2, pt=2, acc=64 (AGPR).
//            launch_bounds(256,2): natural allocation ~110-125 total regs
//            -> 16-waves/CU tier -> 4 blocks/CU (LDS 39.9 KB also allows 4).
//            (256,4) twice forced a 64-reg target + 42-158 MB scratch spill.
//            No afr double-buffer: 4-wave TLP hides the L2 latency instead.
//            32x32x16 f16 MFMA, slot^(p&7) swizzle (conflict-floor pattern).

#define N_S 16
#define HW_S 16384
#define E_S 263936
#define INV2PI 0.15915494309189535f
#define OM2PI  4.774648292756860f   // 30/(2pi)

typedef _Float16 f16x8 __attribute__((ext_vector_type(8)));
typedef _Float16 f16x4 __attribute__((ext_vector_type(4)));
typedef _Float16 f16x2 __attribute__((ext_vector_type(2)));
typedef float f32x4 __attribute__((ext_vector_type(4)));
typedef float f32x16 __attribute__((ext_vector_type(16)));

// ws layout (bytes)
#define WT_OFF   0u          // f16 [16][4][8][256][32]  (8388608 B)
#define W0T_OFF  8388608u    // f32 [16][256][2]  * 30/2pi
#define B0_OFF   8421376u    // f32 [16][256]     * 30/2pi
#define BE_OFF   8437760u    // f32 [16][4][256]  * 1/2pi

__device__ __forceinline__ float fsin(float z) {
  return __builtin_amdgcn_sinf(__builtin_amdgcn_fractf(z));
}

__global__ __launch_bounds__(256) void siren_pre(
    const float* __restrict__ wo, const float* __restrict__ w0,
    const float* __restrict__ b0, const float* __restrict__ wsh,
    const float* __restrict__ bsh, char* __restrict__ ws)
{
  __shared__ float tile[64][65];
  int b = blockIdx.x, t = threadIdx.x;
  if (b < 1024) {
    int n = b >> 6, rem = b & 63, l = rem >> 4, sub = rem & 15;
    int tk = sub >> 2, te = sub & 3;
    int e_loc = t & 63, ksub = t >> 6;
    const float* wo_n = wo + (size_t)n * E_S + 768 + l * 65792;
    const float* wsh_l = wsh + l * 65536;
    for (int r = 0; r < 16; ++r) {
      int k_loc = ksub * 16 + r;
      int k = tk * 64 + k_loc, e = te * 64 + e_loc;
      tile[k_loc][e_loc] = (wsh_l[k * 256 + e] + wo_n[k * 256 + e]) * INV2PI;
    }
    __syncthreads();
    _Float16* wtl = (_Float16*)(ws + WT_OFF) + (size_t)(n * 4 + l) * 65536;
    int kp = (t & 31) * 2, esub = t >> 5;
    for (int r = 0; r < 8; ++r) {
      int e_loc2 = esub * 8 + r;
      f16x2 hv;
      hv[0] = (_Float16)tile[kp][e_loc2];
      hv[1] = (_Float16)tile[kp + 1][e_loc2];
      int e = te * 64 + e_loc2, k = tk * 64 + kp;
      int c = k >> 5, kin = k & 31;
      *(f16x2*)(wtl + (size_t)c * 8192 + e * 32 + kin) = hv;
    }
  } else if (b == 1024) {
    float* w0t = (float*)(ws + W0T_OFF);
    float* b0e = (float*)(ws + B0_OFF);
    for (int idx = t; idx < 4096; idx += 256) {
      int n = idx >> 8, e = idx & 255;
      const float* wo_n = wo + (size_t)n * E_S;
      float2 v;
      v.x = (w0[e] + wo_n[e]) * OM2PI;
      v.y = (w0[256 + e] + wo_n[256 + e]) * OM2PI;
      *(float2*)(w0t + (n * 256 + e) * 2) = v;
      b0e[n * 256 + e] = (b0[e] + wo_n[512 + e]) * OM2PI;
    }
  } else {
    float* be = (float*)(ws + BE_OFF);
    for (int idx = t; idx < 16384; idx += 256) {
      int n = idx >> 10, rem = idx & 1023, l = rem >> 8, e = rem & 255;
      be[(n * 4 + l) * 256 + e] =
          (bsh[l * 256 + e] + wo[(size_t)n * E_S + 768 + l * 65792 + 65536 + e]) * INV2PI;
    }
  }
}

__global__ __launch_bounds__(256, 2) void siren_main(
    const float* __restrict__ x, const char* __restrict__ ws,
    const float* __restrict__ w_out, const float* __restrict__ b_out,
    const float* __restrict__ out_scale, float* __restrict__ out)
{
  __shared__ __align__(16) unsigned char sH[32768];  // H[64 p][256 e] f16, slot^(p&7) swizzle
  __shared__ float sWf[768];        // w_out [256][3]
  __shared__ float sRed[4][64][3];  // per-wave partials
  __shared__ float sFin[192];       // final [64][3]

  int tid = threadIdx.x;
  int lane = tid & 63, eq = tid >> 6;  // wave = e-quarter (64 e x 64 p)
  int l31 = lane & 31, lh = lane >> 5; // 32x32 fragment row / k-half
  int l317 = l31 & 7;
  int bid = blockIdx.x;
  int n = bid & 15, tile = bid >> 4;   // sample n -> XCD n&7 (L2 locality)

  const char* wt_n = ws + WT_OFF + (size_t)n * 524288;

  // stage w_out once (read only in epilogue)
  for (int i = tid; i < 768; i += 256) sWf[i] = w_out[i];

  // ---- layer 0 in fp32 (weights pre-scaled by 30/2pi) -> sH
  {
    const float* xp = x + ((size_t)n * HW_S + (size_t)tile * 64) * 2;
    int p = tid & 63;
    float2 xv = *(const float2*)(xp + p * 2);
    const float* w0t = (const float*)(ws + W0T_OFF) + n * 512;
    const float* b0e = (const float*)(ws + B0_OFF) + n * 256;
    int swz = (p & 7) << 4;
    unsigned char* hrow = sH + p * 512;
#pragma unroll
    for (int it = 0; it < 8; ++it) {
      int eg = (tid >> 6) * 8 + it;    // 0..31, wave-uniform
      int e0 = eg * 8;
      f32x4 wa = *(const f32x4*)(w0t + e0 * 2);
      f32x4 wb = *(const f32x4*)(w0t + e0 * 2 + 4);
      f32x4 wc = *(const f32x4*)(w0t + e0 * 2 + 8);
      f32x4 wd = *(const f32x4*)(w0t + e0 * 2 + 12);
      f32x4 ba = *(const f32x4*)(b0e + e0);
      f32x4 bb = *(const f32x4*)(b0e + e0 + 4);
      f16x8 hv;
      hv[0] = (_Float16)fsin(fmaf(xv.y, wa[1], fmaf(xv.x, wa[0], ba[0])));
      hv[1] = (_Float16)fsin(fmaf(xv.y, wa[3], fmaf(xv.x, wa[2], ba[1])));
      hv[2] = (_Float16)fsin(fmaf(xv.y, wb[1], fmaf(xv.x, wb[0], ba[2])));
      hv[3] = (_Float16)fsin(fmaf(xv.y, wb[3], fmaf(xv.x, wb[2], ba[3])));
      hv[4] = (_Float16)fsin(fmaf(xv.y, wc[1], fmaf(xv.x, wc[0], bb[0])));
      hv[5] = (_Float16)fsin(fmaf(xv.y, wc[3], fmaf(xv.x, wc[2], bb[1])));
      hv[6] = (_Float16)fsin(fmaf(xv.y, wd[1], fmaf(xv.x, wd[0], bb[2])));
      hv[7] = (_Float16)fsin(fmaf(xv.y, wd[3], fmaf(xv.x, wd[2], bb[3])));
      *(f16x8*)(hrow + ((eg * 16) ^ swz)) = hv;
    }
  }
  __syncthreads();

  const float* be_n = (const float*)(ws + BE_OFF) + n * 1024;

  // afr lane base: e = eq*64 + et*32 + l31, byte = e*64 + lh*16 (+ et*2048 + kh*32 imm)
  const unsigned char* wp =
      (const unsigned char*)wt_n + (eq * 64 + l31) * 64 + lh * 16;

  // bfr lane base (slot-swizzled rows): row l31 (+ pt*16384 via imm)
  const unsigned char* hbase = sH + l31 * 512;

  f32x16 acc[2][2];

  for (int l = 0; l < 4; ++l) {
    // bias -> acc: e = eq*64 + et*32 + q*8 + lh*4 + j (j=0..3), reg = q*4+j
    const float* bias = be_n + l * 256 + eq * 64 + lh * 4;
#pragma unroll
    for (int et = 0; et < 2; ++et) {
#pragma unroll
      for (int q = 0; q < 4; ++q) {
        f32x4 bv = *(const f32x4*)(bias + et * 32 + q * 8);
#pragma unroll
        for (int j = 0; j < 4; ++j) {
#pragma unroll
          for (int pt = 0; pt < 2; ++pt) acc[et][pt][q * 4 + j] = bv[j];
        }
      }
    }
#pragma unroll
    for (int c = 0; c < 8; ++c) {
      f16x8 a0 = *(const f16x8*)(wp + 0);
      f16x8 a1 = *(const f16x8*)(wp + 32);
      f16x8 a2 = *(const f16x8*)(wp + 2048);
      f16x8 a3 = *(const f16x8*)(wp + 2080);
      wp += 16384;
      // slot index = c*4 + kh*2 + lh, stored at slot ^ (l31&7)
      int s0 = (((c * 4 + 0) | lh) ^ l317) << 4;
      int s1 = (((c * 4 + 2) | lh) ^ l317) << 4;
      f16x8 b0f[2], b1f[2];
#pragma unroll
      for (int pt = 0; pt < 2; ++pt) {
        b0f[pt] = *(const f16x8*)(hbase + pt * 16384 + s0);
        b1f[pt] = *(const f16x8*)(hbase + pt * 16384 + s1);
      }
#pragma unroll
      for (int pt = 0; pt < 2; ++pt) {
        acc[0][pt] = __builtin_amdgcn_mfma_f32_32x32x16_f16(a0, b0f[pt], acc[0][pt], 0, 0, 0);
        acc[0][pt] = __builtin_amdgcn_mfma_f32_32x32x16_f16(a1, b1f[pt], acc[0][pt], 0, 0, 0);
        acc[1][pt] = __builtin_amdgcn_mfma_f32_32x32x16_f16(a2, b0f[pt], acc[1][pt], 0, 0, 0);
        acc[1][pt] = __builtin_amdgcn_mfma_f32_32x32x16_f16(a3, b1f[pt], acc[1][pt], 0, 0, 0);
      }
    }
    if (l < 3) {
      __syncthreads();  // all waves done reading layer-l H
      unsigned char* wrow = sH + l31 * 512 + lh * 8;
#pragma unroll
      for (int et = 0; et < 2; ++et) {
#pragma unroll
        for (int q = 0; q < 4; ++q) {
          int so = ((eq * 8 + et * 4 + q) ^ l317) << 4;
#pragma unroll
          for (int pt = 0; pt < 2; ++pt) {
            f16x4 hv;
#pragma unroll
            for (int j = 0; j < 4; ++j)
              hv[j] = (_Float16)fsin(acc[et][pt][q * 4 + j]);
            *(f16x4*)(wrow + pt * 16384 + so) = hv;
          }
        }
      }
      __syncthreads();  // new H visible
    }
  }

  // ---- epilogue: h = sin(acc), out = (h @ w_out + b_out) * out_scale
  float part[2][3];
#pragma unroll
  for (int pt = 0; pt < 2; ++pt)
#pragma unroll
    for (int co = 0; co < 3; ++co) part[pt][co] = 0.f;
#pragma unroll
  for (int et = 0; et < 2; ++et) {
#pragma unroll
    for (int q = 0; q < 4; ++q) {
#pragma unroll
      for (int j = 0; j < 4; ++j) {
        int e = eq * 64 + et * 32 + q * 8 + lh * 4 + j;
        float wc0 = sWf[e * 3 + 0], wc1 = sWf[e * 3 + 1], wc2 = sWf[e * 3 + 2];
#pragma unroll
        for (int pt = 0; pt < 2; ++pt) {
          float h = fsin(acc[et][pt][q * 4 + j]);
          part[pt][0] = fmaf(h, wc0, part[pt][0]);
          part[pt][1] = fmaf(h, wc1, part[pt][1]);
          part[pt][2] = fmaf(h, wc2, part[pt][2]);
        }
      }
    }
  }
#pragma unroll
  for (int pt = 0; pt < 2; ++pt)
#pragma unroll
    for (int co = 0; co < 3; ++co)
      part[pt][co] += __shfl_xor(part[pt][co], 32);
  if (lane < 32) {
#pragma unroll
    for (int pt = 0; pt < 2; ++pt) {
      int p = pt * 32 + l31;
#pragma unroll
      for (int co = 0; co < 3; ++co)
        sRed[eq][p][co] = part[pt][co];
    }
  }
  __syncthreads();
  if (tid < 64) {
    int p = tid;
#pragma unroll
    for (int co = 0; co < 3; ++co)
      sFin[p * 3 + co] = (sRed[0][p][co] + sRed[1][p][co] +
                          sRed[2][p][co] + sRed[3][p][co] +
                          b_out[co]) * out_scale[co];
  }
  __syncthreads();
  float* op = out + ((size_t)n * HW_S + (size_t)tile * 64) * 3;
  if (tid < 192) op[tid] = sFin[tid];
}

extern "C" void kernel_launch(void* const* d_in, const int* in_sizes, int n_in,
                              void* d_out, int out_size, void* d_ws, size_t ws_size,
                              hipStream_t stream) {
  const float* x      = (const float*)d_in[0];
  const float* wo     = (const float*)d_in[1];
  const float* w0     = (const float*)d_in[2];
  const float* b0     = (const float*)d_in[3];
  const float* wsh    = (const float*)d_in[4];
  const float* bsh    = (const float*)d_in[5];
  const float* w_out  = (const float*)d_in[6];
  const float* b_out  = (const float*)d_in[7];
  const float* oscale = (const float*)d_in[8];
  float* out = (float*)d_out;
  char* ws = (char*)d_ws;

  siren_pre<<<1026, 256, 0, stream>>>(wo, w0, b0, wsh, bsh, ws);
  siren_main<<<4096, 256, 0, stream>>>(x, ws, w_out, b_out, oscale, out);
}

// Round 11
// 208.881 us; speedup vs baseline: 1.0251x; 1.0160x over previous
//
#include <hip/hip_runtime.h>

// SIREN hypernetwork, round 11 = round-10 + W register prefetch + (256,3).
// Round 9 (prefetch, forced 64-reg) spilled; round 10 (no-spill, no prefetch)
// exposed serial L2 latency. This is the untested cell: prefetch AND no-spill.
// launch_bounds(256,3) caps unified regs at 170: ~84 VGPR + 64 AGPR = 148 fits
// -> 3 waves/SIMD (3 blocks/CU; LDS 39.9 KB allows 4, regs bind at 3).
// siren_main: 4096 blocks = 16 samples x 256 tiles of 64 points, 256 thr,
//            4 waves = e-quarters (64e x 64p): et=2, pt=2, acc=64 AGPR.
//            32x32x16 f16 MFMA, slot^(p&7) swizzle (bank-conflict floor),
//            linear W running pointer + one-chunk-ahead register prefetch.

#define N_S 16
#define HW_S 16384
#define E_S 263936
#define INV2PI 0.15915494309189535f
#define OM2PI  4.774648292756860f   // 30/(2pi)

typedef _Float16 f16x8 __attribute__((ext_vector_type(8)));
typedef _Float16 f16x4 __attribute__((ext_vector_type(4)));
typedef _Float16 f16x2 __attribute__((ext_vector_type(2)));
typedef float f32x4 __attribute__((ext_vector_type(4)));
typedef float f32x16 __attribute__((ext_vector_type(16)));

// ws layout (bytes)
#define WT_OFF   0u          // f16 [16][4][8][256][32]  (8388608 B)
#define W0T_OFF  8388608u    // f32 [16][256][2]  * 30/2pi
#define B0_OFF   8421376u    // f32 [16][256]     * 30/2pi
#define BE_OFF   8437760u    // f32 [16][4][256]  * 1/2pi

__device__ __forceinline__ float fsin(float z) {
  return __builtin_amdgcn_sinf(__builtin_amdgcn_fractf(z));
}

__global__ __launch_bounds__(256) void siren_pre(
    const float* __restrict__ wo, const float* __restrict__ w0,
    const float* __restrict__ b0, const float* __restrict__ wsh,
    const float* __restrict__ bsh, char* __restrict__ ws)
{
  __shared__ float tile[64][65];
  int b = blockIdx.x, t = threadIdx.x;
  if (b < 1024) {
    int n = b >> 6, rem = b & 63, l = rem >> 4, sub = rem & 15;
    int tk = sub >> 2, te = sub & 3;
    int e_loc = t & 63, ksub = t >> 6;
    const float* wo_n = wo + (size_t)n * E_S + 768 + l * 65792;
    const float* wsh_l = wsh + l * 65536;
    for (int r = 0; r < 16; ++r) {
      int k_loc = ksub * 16 + r;
      int k = tk * 64 + k_loc, e = te * 64 + e_loc;
      tile[k_loc][e_loc] = (wsh_l[k * 256 + e] + wo_n[k * 256 + e]) * INV2PI;
    }
    __syncthreads();
    _Float16* wtl = (_Float16*)(ws + WT_OFF) + (size_t)(n * 4 + l) * 65536;
    int kp = (t & 31) * 2, esub = t >> 5;
    for (int r = 0; r < 8; ++r) {
      int e_loc2 = esub * 8 + r;
      f16x2 hv;
      hv[0] = (_Float16)tile[kp][e_loc2];
      hv[1] = (_Float16)tile[kp + 1][e_loc2];
      int e = te * 64 + e_loc2, k = tk * 64 + kp;
      int c = k >> 5, kin = k & 31;
      *(f16x2*)(wtl + (size_t)c * 8192 + e * 32 + kin) = hv;
    }
  } else if (b == 1024) {
    float* w0t = (float*)(ws + W0T_OFF);
    float* b0e = (float*)(ws + B0_OFF);
    for (int idx = t; idx < 4096; idx += 256) {
      int n = idx >> 8, e = idx & 255;
      const float* wo_n = wo + (size_t)n * E_S;
      float2 v;
      v.x = (w0[e] + wo_n[e]) * OM2PI;
      v.y = (w0[256 + e] + wo_n[256 + e]) * OM2PI;
      *(float2*)(w0t + (n * 256 + e) * 2) = v;
      b0e[n * 256 + e] = (b0[e] + wo_n[512 + e]) * OM2PI;
    }
  } else {
    float* be = (float*)(ws + BE_OFF);
    for (int idx = t; idx < 16384; idx += 256) {
      int n = idx >> 10, rem = idx & 1023, l = rem >> 8, e = rem & 255;
      be[(n * 4 + l) * 256 + e] =
          (bsh[l * 256 + e] + wo[(size_t)n * E_S + 768 + l * 65792 + 65536 + e]) * INV2PI;
    }
  }
}

__global__ __launch_bounds__(256, 3) void siren_main(
    const float* __restrict__ x, const char* __restrict__ ws,
    const float* __restrict__ w_out, const float* __restrict__ b_out,
    const float* __restrict__ out_scale, float* __restrict__ out)
{
  __shared__ __align__(16) unsigned char sH[32768];  // H[64 p][256 e] f16, slot^(p&7) swizzle
  __shared__ float sWf[768];        // w_out [256][3]
  __shared__ float sRed[4][64][3];  // per-wave partials
  __shared__ float sFin[192];       // final [64][3]

  int tid = threadIdx.x;
  int lane = tid & 63, eq = tid >> 6;  // wave = e-quarter (64 e x 64 p)
  int l31 = lane & 31, lh = lane >> 5; // 32x32 fragment row / k-half
  int l317 = l31 & 7;
  int bid = blockIdx.x;
  int n = bid & 15, tile = bid >> 4;   // sample n -> XCD n&7 (L2 locality)

  const char* wt_n = ws + WT_OFF + (size_t)n * 524288;

  // stage w_out once (read only in epilogue)
  for (int i = tid; i < 768; i += 256) sWf[i] = w_out[i];

  // ---- layer 0 in fp32 (weights pre-scaled by 30/2pi) -> sH
  {
    const float* xp = x + ((size_t)n * HW_S + (size_t)tile * 64) * 2;
    int p = tid & 63;
    float2 xv = *(const float2*)(xp + p * 2);
    const float* w0t = (const float*)(ws + W0T_OFF) + n * 512;
    const float* b0e = (const float*)(ws + B0_OFF) + n * 256;
    int swz = (p & 7) << 4;
    unsigned char* hrow = sH + p * 512;
#pragma unroll
    for (int it = 0; it < 8; ++it) {
      int eg = (tid >> 6) * 8 + it;    // 0..31, wave-uniform
      int e0 = eg * 8;
      f32x4 wa = *(const f32x4*)(w0t + e0 * 2);
      f32x4 wb = *(const f32x4*)(w0t + e0 * 2 + 4);
      f32x4 wc = *(const f32x4*)(w0t + e0 * 2 + 8);
      f32x4 wd = *(const f32x4*)(w0t + e0 * 2 + 12);
      f32x4 ba = *(const f32x4*)(b0e + e0);
      f32x4 bb = *(const f32x4*)(b0e + e0 + 4);
      f16x8 hv;
      hv[0] = (_Float16)fsin(fmaf(xv.y, wa[1], fmaf(xv.x, wa[0], ba[0])));
      hv[1] = (_Float16)fsin(fmaf(xv.y, wa[3], fmaf(xv.x, wa[2], ba[1])));
      hv[2] = (_Float16)fsin(fmaf(xv.y, wb[1], fmaf(xv.x, wb[0], ba[2])));
      hv[3] = (_Float16)fsin(fmaf(xv.y, wb[3], fmaf(xv.x, wb[2], ba[3])));
      hv[4] = (_Float16)fsin(fmaf(xv.y, wc[1], fmaf(xv.x, wc[0], bb[0])));
      hv[5] = (_Float16)fsin(fmaf(xv.y, wc[3], fmaf(xv.x, wc[2], bb[1])));
      hv[6] = (_Float16)fsin(fmaf(xv.y, wd[1], fmaf(xv.x, wd[0], bb[2])));
      hv[7] = (_Float16)fsin(fmaf(xv.y, wd[3], fmaf(xv.x, wd[2], bb[3])));
      *(f16x8*)(hrow + ((eg * 16) ^ swz)) = hv;
    }
  }
  __syncthreads();

  const float* be_n = (const float*)(ws + BE_OFF) + n * 1024;

  // afr lane base: e = eq*64 + et*32 + l31, byte = e*64 + lh*16 (+ et*2048 + kh*32 imm)
  const unsigned char* wp =
      (const unsigned char*)wt_n + (eq * 64 + l31) * 64 + lh * 16;

  // bfr lane base (slot-swizzled rows): row l31 (+ pt*16384 via imm)
  const unsigned char* hbase = sH + l31 * 512;

  f32x16 acc[2][2];
  f16x8 a0, a1, a2, a3, n0, n1, n2, n3;
  a0 = *(const f16x8*)(wp + 0);
  a1 = *(const f16x8*)(wp + 32);
  a2 = *(const f16x8*)(wp + 2048);
  a3 = *(const f16x8*)(wp + 2080);

  for (int l = 0; l < 4; ++l) {
    // bias -> acc: e = eq*64 + et*32 + q*8 + lh*4 + j (j=0..3), reg = q*4+j
    const float* bias = be_n + l * 256 + eq * 64 + lh * 4;
#pragma unroll
    for (int et = 0; et < 2; ++et) {
#pragma unroll
      for (int q = 0; q < 4; ++q) {
        f32x4 bv = *(const f32x4*)(bias + et * 32 + q * 8);
#pragma unroll
        for (int j = 0; j < 4; ++j) {
#pragma unroll
          for (int pt = 0; pt < 2; ++pt) acc[et][pt][q * 4 + j] = bv[j];
        }
      }
    }
#pragma unroll
    for (int c = 0; c < 8; ++c) {
      if (c < 7 || l < 3) {  // prefetch next chunk (linear across layers)
        wp += 16384;
        n0 = *(const f16x8*)(wp + 0);
        n1 = *(const f16x8*)(wp + 32);
        n2 = *(const f16x8*)(wp + 2048);
        n3 = *(const f16x8*)(wp + 2080);
      }
      // slot index = c*4 + kh*2 + lh, stored at slot ^ (l31&7)
      int s0 = (((c * 4 + 0) | lh) ^ l317) << 4;
      int s1 = (((c * 4 + 2) | lh) ^ l317) << 4;
      f16x8 b0f[2], b1f[2];
#pragma unroll
      for (int pt = 0; pt < 2; ++pt) {
        b0f[pt] = *(const f16x8*)(hbase + pt * 16384 + s0);
        b1f[pt] = *(const f16x8*)(hbase + pt * 16384 + s1);
      }
#pragma unroll
      for (int pt = 0; pt < 2; ++pt) {
        acc[0][pt] = __builtin_amdgcn_mfma_f32_32x32x16_f16(a0, b0f[pt], acc[0][pt], 0, 0, 0);
        acc[0][pt] = __builtin_amdgcn_mfma_f32_32x32x16_f16(a1, b1f[pt], acc[0][pt], 0, 0, 0);
        acc[1][pt] = __builtin_amdgcn_mfma_f32_32x32x16_f16(a2, b0f[pt], acc[1][pt], 0, 0, 0);
        acc[1][pt] = __builtin_amdgcn_mfma_f32_32x32x16_f16(a3, b1f[pt], acc[1][pt], 0, 0, 0);
      }
      a0 = n0; a1 = n1; a2 = n2; a3 = n3;
    }
    if (l < 3) {
      __syncthreads();  // all waves done reading layer-l H
      unsigned char* wrow = sH + l31 * 512 + lh * 8;
#pragma unroll
      for (int et = 0; et < 2; ++et) {
#pragma unroll
        for (int q = 0; q < 4; ++q) {
          int so = ((eq * 8 + et * 4 + q) ^ l317) << 4;
#pragma unroll
          for (int pt = 0; pt < 2; ++pt) {
            f16x4 hv;
#pragma unroll
            for (int j = 0; j < 4; ++j)
              hv[j] = (_Float16)fsin(acc[et][pt][q * 4 + j]);
            *(f16x4*)(wrow + pt * 16384 + so) = hv;
          }
        }
      }
      __syncthreads();  // new H visible
    }
  }

  // ---- epilogue: h = sin(acc), out = (h @ w_out + b_out) * out_scale
  float part[2][3];
#pragma unroll
  for (int pt = 0; pt < 2; ++pt)
#pragma unroll
    for (int co = 0; co < 3; ++co) part[pt][co] = 0.f;
#pragma unroll
  for (int et = 0; et < 2; ++et) {
#pragma unroll
    for (int q = 0; q < 4; ++q) {
#pragma unroll
      for (int j = 0; j < 4; ++j) {
        int e = eq * 64 + et * 32 + q * 8 + lh * 4 + j;
        float wc0 = sWf[e * 3 + 0], wc1 = sWf[e * 3 + 1], wc2 = sWf[e * 3 + 2];
#pragma unroll
        for (int pt = 0; pt < 2; ++pt) {
          float h = fsin(acc[et][pt][q * 4 + j]);
          part[pt][0] = fmaf(h, wc0, part[pt][0]);
          part[pt][1] = fmaf(h, wc1, part[pt][1]);
          part[pt][2] = fmaf(h, wc2, part[pt][2]);
        }
      }
    }
  }
#pragma unroll
  for (int pt = 0; pt < 2; ++pt)
#pragma unroll
    for (int co = 0; co < 3; ++co)
      part[pt][co] += __shfl_xor(part[pt][co], 32);
  if (lane < 32) {
#pragma unroll
    for (int pt = 0; pt < 2; ++pt) {
      int p = pt * 32 + l31;
#pragma unroll
      for (int co = 0; co < 3; ++co)
        sRed[eq][p][co] = part[pt][co];
    }
  }
  __syncthreads();
  if (tid < 64) {
    int p = tid;
#pragma unroll
    for (int co = 0; co < 3; ++co)
      sFin[p * 3 + co] = (sRed[0][p][co] + sRed[1][p][co] +
                          sRed[2][p][co] + sRed[3][p][co] +
                          b_out[co]) * out_scale[co];
  }
  __syncthreads();
  float* op = out + ((size_t)n * HW_S + (size_t)tile * 64) * 3;
  if (tid < 192) op[tid] = sFin[tid];
}

extern "C" void kernel_launch(void* const* d_in, const int* in_sizes, int n_in,
                              void* d_out, int out_size, void* d_ws, size_t ws_size,
                              hipStream_t stream) {
  const float* x      = (const float*)d_in[0];
  const float* wo     = (const float*)d_in[1];
  const float* w0     = (const float*)d_in[2];
  const float* b0     = (const float*)d_in[3];
  const float* wsh    = (const float*)d_in[4];
  const float* bsh    = (const float*)d_in[5];
  const float* w_out  = (const float*)d_in[6];
  const float* b_out  = (const float*)d_in[7];
  const float* oscale = (const float*)d_in[8];
  float* out = (float*)d_out;
  char* ws = (char*)d_ws;

  siren_pre<<<1026, 256, 0, stream>>>(wo, w0, b0, wsh, bsh, ws);
  siren_main<<<4096, 256, 0, stream>>>(x, ws, w_out, b_out, oscale, out);
}

// Round 12
// 165.079 us; speedup vs baseline: 1.2971x; 1.2653x over previous
//
#include <hip/hip_runtime.h>

// SIREN hypernetwork, round 12 = round 4 (the 163us champion) + two
// register-neutral boundary optimizations:
//  (1) sin+f16-pack computed into hpack[] BEFORE the first boundary barrier
//      (reuses dead afr/bfr regs; only bare ds_writes sit between barriers)
//  (2) s_setprio(1) around the MFMA c-loop, (0) elsewhere — 2 drifting
//      blocks/CU give the scheduler real phase diversity to arbitrate.
// Geometry (R4): 2048 blocks = 16 samples x 128 tiles of 128 p, 256 thr,
// 4 waves = e-quarters, et=4 x pt=8, 16x16x32 MFMA, afr direct from L2
// (barrier-free c-loop -> compiler pipelines loads), slot^(p&7) swizzle.
// Register budget is EXACTLY full: 128 VGPR + 128 AGPR = 256 = 2 waves/SIMD.

#define N_S 16
#define HW_S 16384
#define E_S 263936
#define INV2PI 0.15915494309189535f
#define OM2PI  4.774648292756860f   // 30/(2pi)

typedef _Float16 f16x8 __attribute__((ext_vector_type(8)));
typedef _Float16 f16x4 __attribute__((ext_vector_type(4)));
typedef _Float16 f16x2 __attribute__((ext_vector_type(2)));
typedef float f32x4 __attribute__((ext_vector_type(4)));

// ws layout (bytes)
#define WT_OFF   0u          // f16 [16][4][8][256][32]  (8388608 B)
#define W0T_OFF  8388608u    // f32 [16][256][2]  * 30/2pi
#define B0_OFF   8421376u    // f32 [16][256]     * 30/2pi
#define BE_OFF   8437760u    // f32 [16][4][256]  * 1/2pi

__device__ __forceinline__ float fsin(float z) {
  return __builtin_amdgcn_sinf(__builtin_amdgcn_fractf(z));
}

__global__ __launch_bounds__(256) void siren_pre(
    const float* __restrict__ wo, const float* __restrict__ w0,
    const float* __restrict__ b0, const float* __restrict__ wsh,
    const float* __restrict__ bsh, char* __restrict__ ws)
{
  __shared__ float tile[64][65];
  int b = blockIdx.x, t = threadIdx.x;
  if (b < 1024) {
    int n = b >> 6, rem = b & 63, l = rem >> 4, sub = rem & 15;
    int tk = sub >> 2, te = sub & 3;
    int e_loc = t & 63, ksub = t >> 6;
    const float* wo_n = wo + (size_t)n * E_S + 768 + l * 65792;
    const float* wsh_l = wsh + l * 65536;
    for (int r = 0; r < 16; ++r) {
      int k_loc = ksub * 16 + r;
      int k = tk * 64 + k_loc, e = te * 64 + e_loc;
      tile[k_loc][e_loc] = (wsh_l[k * 256 + e] + wo_n[k * 256 + e]) * INV2PI;
    }
    __syncthreads();
    _Float16* wtl = (_Float16*)(ws + WT_OFF) + (size_t)(n * 4 + l) * 65536;
    int kp = (t & 31) * 2, esub = t >> 5;
    for (int r = 0; r < 8; ++r) {
      int e_loc2 = esub * 8 + r;
      f16x2 hv;
      hv[0] = (_Float16)tile[kp][e_loc2];
      hv[1] = (_Float16)tile[kp + 1][e_loc2];
      int e = te * 64 + e_loc2, k = tk * 64 + kp;
      int c = k >> 5, kin = k & 31;
      *(f16x2*)(wtl + (size_t)c * 8192 + e * 32 + kin) = hv;
    }
  } else if (b == 1024) {
    float* w0t = (float*)(ws + W0T_OFF);
    float* b0e = (float*)(ws + B0_OFF);
    for (int idx = t; idx < 4096; idx += 256) {
      int n = idx >> 8, e = idx & 255;
      const float* wo_n = wo + (size_t)n * E_S;
      float2 v;
      v.x = (w0[e] + wo_n[e]) * OM2PI;
      v.y = (w0[256 + e] + wo_n[256 + e]) * OM2PI;
      *(float2*)(w0t + (n * 256 + e) * 2) = v;
      b0e[n * 256 + e] = (b0[e] + wo_n[512 + e]) * OM2PI;
    }
  } else {
    float* be = (float*)(ws + BE_OFF);
    for (int idx = t; idx < 16384; idx += 256) {
      int n = idx >> 10, rem = idx & 1023, l = rem >> 8, e = rem & 255;
      be[(n * 4 + l) * 256 + e] =
          (bsh[l * 256 + e] + wo[(size_t)n * E_S + 768 + l * 65792 + 65536 + e]) * INV2PI;
    }
  }
}

__global__ __launch_bounds__(256, 2) void siren_main(
    const float* __restrict__ x, const char* __restrict__ ws,
    const float* __restrict__ w_out, const float* __restrict__ b_out,
    const float* __restrict__ out_scale, float* __restrict__ out)
{
  __shared__ __align__(16) unsigned char sH[65536];  // H[128 p][256 e] f16, row-XOR-swizzled
  __shared__ float sWf[768];        // w_out [256][3]
  __shared__ float sRed[4][128][3]; // per-wave partials
  __shared__ float sFin[384];       // final [128][3]

  int tid = threadIdx.x;
  int lane = tid & 63, eq = tid >> 6;  // wave = e-quarter
  int g = lane >> 4, li = lane & 15;
  int bid = blockIdx.x;
  int n = bid & 15, tile = bid >> 4;   // sample n -> XCD n&7 (L2 locality)

  const char* wt_n = ws + WT_OFF + (size_t)n * 524288;

  // stage w_out once (read only in epilogue)
  for (int i = tid; i < 768; i += 256) sWf[i] = w_out[i];

  // ---- layer 0 in fp32 (weights pre-scaled by 30/2pi) -> sH
  {
    const float* xp = x + ((size_t)n * HW_S + (size_t)tile * 128) * 2;
    int p = tid & 127;
    float2 xv = *(const float2*)(xp + p * 2);
    const float* w0t = (const float*)(ws + W0T_OFF) + n * 512;
    const float* b0e = (const float*)(ws + B0_OFF) + n * 256;
    int swz = (p & 7) << 4;
    unsigned char* hrow = sH + p * 512;
#pragma unroll
    for (int it = 0; it < 16; ++it) {
      int eg = (tid >> 7) * 16 + it;   // 0..31, wave-uniform
      int e0 = eg * 8;
      f32x4 wa = *(const f32x4*)(w0t + e0 * 2);
      f32x4 wb = *(const f32x4*)(w0t + e0 * 2 + 4);
      f32x4 wc = *(const f32x4*)(w0t + e0 * 2 + 8);
      f32x4 wd = *(const f32x4*)(w0t + e0 * 2 + 12);
      f32x4 ba = *(const f32x4*)(b0e + e0);
      f32x4 bb = *(const f32x4*)(b0e + e0 + 4);
      f16x8 hv;
      hv[0] = (_Float16)fsin(fmaf(xv.y, wa[1], fmaf(xv.x, wa[0], ba[0])));
      hv[1] = (_Float16)fsin(fmaf(xv.y, wa[3], fmaf(xv.x, wa[2], ba[1])));
      hv[2] = (_Float16)fsin(fmaf(xv.y, wb[1], fmaf(xv.x, wb[0], ba[2])));
      hv[3] = (_Float16)fsin(fmaf(xv.y, wb[3], fmaf(xv.x, wb[2], ba[3])));
      hv[4] = (_Float16)fsin(fmaf(xv.y, wc[1], fmaf(xv.x, wc[0], bb[0])));
      hv[5] = (_Float16)fsin(fmaf(xv.y, wc[3], fmaf(xv.x, wc[2], bb[1])));
      hv[6] = (_Float16)fsin(fmaf(xv.y, wd[1], fmaf(xv.x, wd[0], bb[2])));
      hv[7] = (_Float16)fsin(fmaf(xv.y, wd[3], fmaf(xv.x, wd[2], bb[3])));
      *(f16x8*)(hrow + ((eg * 16) ^ swz)) = hv;
    }
  }
  __syncthreads();

  const float* be_n = (const float*)(ws + BE_OFF) + n * 1024;
  int laneoff = (eq * 64 + li) * 64 + g * 16;  // byte offset of lane's W row slice
  f32x4 acc[4][8];

  for (int l = 0; l < 4; ++l) {
    const float* bias = be_n + l * 256;
#pragma unroll
    for (int et = 0; et < 4; ++et) {
      f32x4 bv = *(const f32x4*)(bias + eq * 64 + et * 16 + g * 4);
#pragma unroll
      for (int pt = 0; pt < 8; ++pt) acc[et][pt] = bv;
    }
    const char* wl = wt_n + (size_t)l * 131072 + laneoff;
    __builtin_amdgcn_s_setprio(1);
#pragma unroll
    for (int c = 0; c < 8; ++c) {
      f16x8 afr[4], bfr[8];
#pragma unroll
      for (int et = 0; et < 4; ++et)
        afr[et] = *(const f16x8*)(wl + c * 16384 + et * 1024);
#pragma unroll
      for (int pt = 0; pt < 8; ++pt) {
        int p = pt * 16 + li;
        bfr[pt] = *(const f16x8*)(sH + p * 512 + ((c * 64 + g * 16) ^ ((p & 7) << 4)));
      }
#pragma unroll
      for (int et = 0; et < 4; ++et)
#pragma unroll
        for (int pt = 0; pt < 8; ++pt)
          acc[et][pt] = __builtin_amdgcn_mfma_f32_16x16x32_f16(afr[et], bfr[pt], acc[et][pt], 0, 0, 0);
    }
    __builtin_amdgcn_s_setprio(0);
    if (l < 3) {
      // sin + f16 pack BEFORE the barrier (acc is ready; no LDS dependence).
      // hpack reuses the afr/bfr registers that are dead outside the c-loop.
      f16x4 hpack[4][8];
#pragma unroll
      for (int et = 0; et < 4; ++et)
#pragma unroll
        for (int pt = 0; pt < 8; ++pt)
#pragma unroll
          for (int r = 0; r < 4; ++r)
            hpack[et][pt][r] = (_Float16)fsin(acc[et][pt][r]);
      __syncthreads();  // all waves done reading layer-l H
#pragma unroll
      for (int et = 0; et < 4; ++et) {
        int eb = eq * 128 + et * 32 + g * 8;   // byte offset of e*2
#pragma unroll
        for (int pt = 0; pt < 8; ++pt) {
          int p = pt * 16 + li;
          *(f16x4*)(sH + p * 512 + (eb ^ ((p & 7) << 4))) = hpack[et][pt];
        }
      }
      __syncthreads();  // new H visible
    }
  }

  // ---- epilogue: h = sin(acc), out = (h @ w_out + b_out) * out_scale
  float part[8][3];
#pragma unroll
  for (int pt = 0; pt < 8; ++pt)
#pragma unroll
    for (int co = 0; co < 3; ++co) part[pt][co] = 0.f;
#pragma unroll
  for (int et = 0; et < 4; ++et) {
#pragma unroll
    for (int r = 0; r < 4; ++r) {
      int e = eq * 64 + et * 16 + g * 4 + r;
      float wc0 = sWf[e * 3 + 0], wc1 = sWf[e * 3 + 1], wc2 = sWf[e * 3 + 2];
#pragma unroll
      for (int pt = 0; pt < 8; ++pt) {
        float h = fsin(acc[et][pt][r]);
        part[pt][0] = fmaf(h, wc0, part[pt][0]);
        part[pt][1] = fmaf(h, wc1, part[pt][1]);
        part[pt][2] = fmaf(h, wc2, part[pt][2]);
      }
    }
  }
#pragma unroll
  for (int pt = 0; pt < 8; ++pt)
#pragma unroll
    for (int co = 0; co < 3; ++co) {
      float v = part[pt][co];
      v += __shfl_xor(v, 16);
      v += __shfl_xor(v, 32);
      part[pt][co] = v;
    }
  if (g == 0) {
#pragma unroll
    for (int pt = 0; pt < 8; ++pt) {
      int p = pt * 16 + li;
#pragma unroll
      for (int co = 0; co < 3; ++co)
        sRed[eq][p][co] = part[pt][co];
    }
  }
  __syncthreads();
  if (tid < 128) {
    int p = tid;
#pragma unroll
    for (int co = 0; co < 3; ++co)
      sFin[p * 3 + co] = (sRed[0][p][co] + sRed[1][p][co] +
                          sRed[2][p][co] + sRed[3][p][co] +
                          b_out[co]) * out_scale[co];
  }
  __syncthreads();
  float* op = out + ((size_t)n * HW_S + (size_t)tile * 128) * 3;
  for (int i = tid; i < 384; i += 256) op[i] = sFin[i];
}

extern "C" void kernel_launch(void* const* d_in, const int* in_sizes, int n_in,
                              void* d_out, int out_size, void* d_ws, size_t ws_size,
                              hipStream_t stream) {
  const float* x      = (const float*)d_in[0];
  const float* wo     = (const float*)d_in[1];
  const float* w0     = (const float*)d_in[2];
  const float* b0     = (const float*)d_in[3];
  const float* wsh    = (const float*)d_in[4];
  const float* bsh    = (const float*)d_in[5];
  const float* w_out  = (const float*)d_in[6];
  const float* b_out  = (const float*)d_in[7];
  const float* oscale = (const float*)d_in[8];
  float* out = (float*)d_out;
  char* ws = (char*)d_ws;

  siren_pre<<<1026, 256, 0, stream>>>(wo, w0, b0, wsh, bsh, ws);
  siren_main<<<2048, 256, 0, stream>>>(x, ws, w_out, b_out, oscale, out);
}